// Round 3
// baseline (3280.630 us; speedup 1.0000x reference)
//
#include <hip/hip_runtime.h>

typedef __bf16 bfrag8 __attribute__((ext_vector_type(8)));
typedef float f32x4 __attribute__((ext_vector_type(4)));
typedef unsigned int u32x4 __attribute__((ext_vector_type(4)));
typedef unsigned short ush;

__device__ __forceinline__ float bf2f(ush s) {
    union { unsigned int u; float f; } un; un.u = ((unsigned int)s) << 16; return un.f;
}
__device__ __forceinline__ ush f2bf(float f) {
    union { float f; unsigned int u; } un; un.f = f;
    unsigned int u = un.u;
    u += 0x7fffu + ((u >> 16) & 1u);   // round-to-nearest-even
    return (ush)(u >> 16);
}

// ---------------------------------------------------------------------------
// Shared GEMM config: 128x128 block tile, 4 waves (64x64 each), BK=32,
// mfma_f32_16x16x32_bf16, LDS tiles in bf16 with pad-40 leading dim.
// Inputs are fp32 in HBM (per reference); converted to bf16 during staging.
// ---------------------------------------------------------------------------
#define BM 128
#define BN 128
#define BK 32
#define LDA 40
#define LDB 40

// GEMM1: C(bf16) = A(fp32) * B(fp32)
__global__ __launch_bounds__(256)
void gemm_ff_bf(const float* __restrict__ A, const float* __restrict__ B,
                ush* __restrict__ C, int M, int N, int K)
{
    __shared__ ush As[BM * LDA];
    __shared__ ush Bs[BN * LDB];

    const int tid  = threadIdx.x;
    const int wave = tid >> 6, lane = tid & 63;
    const int waveM = wave >> 1, waveN = wave & 1;
    const int lrow = lane & 15, quad = lane >> 4;
    const long m0 = (long)blockIdx.y * BM;
    const long n0 = (long)blockIdx.x * BN;

    const f32x4 fzero = {0.f, 0.f, 0.f, 0.f};
    f32x4 acc[4][4];
    #pragma unroll
    for (int i = 0; i < 4; ++i)
        #pragma unroll
        for (int j = 0; j < 4; ++j) acc[i][j] = fzero;

    for (int k0 = 0; k0 < K; k0 += BK) {
        // A tile 128x32 fp32 -> bf16: 1024 float4 chunks, 4 per thread
        #pragma unroll
        for (int i = 0; i < 4; ++i) {
            int c = tid + i * 256;
            int row = c >> 3, cc = c & 7;
            float4 v = *reinterpret_cast<const float4*>(&A[(m0 + row) * (long)K + k0 + cc * 4]);
            ush* p = &As[row * LDA + cc * 4];
            p[0] = f2bf(v.x); p[1] = f2bf(v.y); p[2] = f2bf(v.z); p[3] = f2bf(v.w);
        }
        // B tile 32x128 fp32 -> bf16, transposed into Bs[n][k]
        #pragma unroll
        for (int i = 0; i < 4; ++i) {
            int c = tid + i * 256;
            int krow = c >> 5, nc = c & 31;
            float4 v = *reinterpret_cast<const float4*>(&B[(long)(k0 + krow) * N + n0 + nc * 4]);
            Bs[(nc * 4 + 0) * LDB + krow] = f2bf(v.x);
            Bs[(nc * 4 + 1) * LDB + krow] = f2bf(v.y);
            Bs[(nc * 4 + 2) * LDB + krow] = f2bf(v.z);
            Bs[(nc * 4 + 3) * LDB + krow] = f2bf(v.w);
        }
        __syncthreads();

        bfrag8 af[4], bf[4];
        #pragma unroll
        for (int mi = 0; mi < 4; ++mi)
            af[mi] = *reinterpret_cast<const bfrag8*>(&As[(waveM * 64 + mi * 16 + lrow) * LDA + quad * 8]);
        #pragma unroll
        for (int ni = 0; ni < 4; ++ni)
            bf[ni] = *reinterpret_cast<const bfrag8*>(&Bs[(waveN * 64 + ni * 16 + lrow) * LDB + quad * 8]);
        #pragma unroll
        for (int mi = 0; mi < 4; ++mi)
            #pragma unroll
            for (int ni = 0; ni < 4; ++ni)
                acc[mi][ni] = __builtin_amdgcn_mfma_f32_16x16x32_bf16(af[mi], bf[ni], acc[mi][ni], 0, 0, 0);
        __syncthreads();
    }

    #pragma unroll
    for (int mi = 0; mi < 4; ++mi)
        #pragma unroll
        for (int ni = 0; ni < 4; ++ni)
            #pragma unroll
            for (int r = 0; r < 4; ++r) {
                long row = m0 + waveM * 64 + mi * 16 + quad * 4 + r;
                long col = n0 + waveN * 64 + ni * 16 + lrow;
                C[row * (long)N + col] = f2bf(acc[mi][ni][r]);
            }
}

// GEMM2: C(fp32) = A(bf16) * B(fp32)
__global__ __launch_bounds__(256)
void gemm_bf_f(const ush* __restrict__ A, const float* __restrict__ B,
               float* __restrict__ C, int M, int N, int K)
{
    __shared__ ush As[BM * LDA];
    __shared__ ush Bs[BN * LDB];

    const int tid  = threadIdx.x;
    const int wave = tid >> 6, lane = tid & 63;
    const int waveM = wave >> 1, waveN = wave & 1;
    const int lrow = lane & 15, quad = lane >> 4;
    const long m0 = (long)blockIdx.y * BM;
    const long n0 = (long)blockIdx.x * BN;

    const f32x4 fzero = {0.f, 0.f, 0.f, 0.f};
    f32x4 acc[4][4];
    #pragma unroll
    for (int i = 0; i < 4; ++i)
        #pragma unroll
        for (int j = 0; j < 4; ++j) acc[i][j] = fzero;

    for (int k0 = 0; k0 < K; k0 += BK) {
        // A tile 128x32 bf16: 512 chunks of 8 bf16, 2 per thread
        #pragma unroll
        for (int i = 0; i < 2; ++i) {
            int c = tid + i * 256;
            int row = c >> 2, cc = c & 3;
            u32x4 v = *reinterpret_cast<const u32x4*>(&A[(m0 + row) * (long)K + k0 + cc * 8]);
            *reinterpret_cast<u32x4*>(&As[row * LDA + cc * 8]) = v;
        }
        // B tile 32x128 fp32 -> bf16, transposed
        #pragma unroll
        for (int i = 0; i < 4; ++i) {
            int c = tid + i * 256;
            int krow = c >> 5, nc = c & 31;
            float4 v = *reinterpret_cast<const float4*>(&B[(long)(k0 + krow) * N + n0 + nc * 4]);
            Bs[(nc * 4 + 0) * LDB + krow] = f2bf(v.x);
            Bs[(nc * 4 + 1) * LDB + krow] = f2bf(v.y);
            Bs[(nc * 4 + 2) * LDB + krow] = f2bf(v.z);
            Bs[(nc * 4 + 3) * LDB + krow] = f2bf(v.w);
        }
        __syncthreads();

        bfrag8 af[4], bf[4];
        #pragma unroll
        for (int mi = 0; mi < 4; ++mi)
            af[mi] = *reinterpret_cast<const bfrag8*>(&As[(waveM * 64 + mi * 16 + lrow) * LDA + quad * 8]);
        #pragma unroll
        for (int ni = 0; ni < 4; ++ni)
            bf[ni] = *reinterpret_cast<const bfrag8*>(&Bs[(waveN * 64 + ni * 16 + lrow) * LDB + quad * 8]);
        #pragma unroll
        for (int mi = 0; mi < 4; ++mi)
            #pragma unroll
            for (int ni = 0; ni < 4; ++ni)
                acc[mi][ni] = __builtin_amdgcn_mfma_f32_16x16x32_bf16(af[mi], bf[ni], acc[mi][ni], 0, 0, 0);
        __syncthreads();
    }

    #pragma unroll
    for (int mi = 0; mi < 4; ++mi)
        #pragma unroll
        for (int ni = 0; ni < 4; ++ni)
            #pragma unroll
            for (int r = 0; r < 4; ++r) {
                long row = m0 + waveM * 64 + mi * 16 + quad * 4 + r;
                long col = n0 + waveN * 64 + ni * 16 + lrow;
                C[row * (long)N + col] = acc[mi][ni][r];
            }
}

// ---------------------------------------------------------------------------
// RoPE in-place on q,k halves of qkv (bf16), fp32 cos/sin tables.
// ---------------------------------------------------------------------------
__global__ void rope_kernel(ush* __restrict__ qkv,
                            const float* __restrict__ cosb, const float* __restrict__ sinb)
{
    int idx = blockIdx.x * 256 + threadIdx.x;  // B*S*H*64 = 8388608
    int i = idx & 63;
    int h = (idx >> 6) & 31;
    int s = (idx >> 11) & 2047;
    int b = idx >> 22;
    float c  = cosb[s * 64 + i];
    float sn = sinb[s * 64 + i];
    long base = ((long)(b * 2048 + s)) * 12288 + h * 128 + 2 * i;
    float qr = bf2f(qkv[base]), qi = bf2f(qkv[base + 1]);
    qkv[base]     = f2bf(qr * c - qi * sn);
    qkv[base + 1] = f2bf(qr * sn + qi * c);
    float kr = bf2f(qkv[base + 4096]), ki = bf2f(qkv[base + 4097]);
    qkv[base + 4096] = f2bf(kr * c - ki * sn);
    qkv[base + 4097] = f2bf(kr * sn + ki * c);
}

// ---------------------------------------------------------------------------
// Flash attention (causal, online softmax), bf16 in/out, fp32 accumulators.
// ---------------------------------------------------------------------------
#define LDK 136
#define LDV 72
#define LDP 72

__global__ __launch_bounds__(256)
void attn_kernel(const ush* __restrict__ qkv, ush* __restrict__ y)
{
    __shared__ ush Ks[64 * LDK];    // [kv][d]
    __shared__ ush Vt[128 * LDV];   // [d][kv]
    __shared__ ush Ps[128 * LDP];   // [q][kv]

    const int qt = blockIdx.x;
    const int bh = blockIdx.y;
    const int b = bh >> 5, h = bh & 31;
    const int tid = threadIdx.x, wave = tid >> 6, lane = tid & 63;
    const int lrow = lane & 15, quad = lane >> 4;
    const int q0 = qt * 128;
    const long rs = 12288;
    const ush* qb = qkv + (long)b * 2048 * rs + h * 128;
    const ush* kb = qb + 4096;
    const ush* vb = qb + 8192;
    const float scale = 0.08838834764831845f;  // 1/sqrt(128)

    bfrag8 qf[2][4];
    #pragma unroll
    for (int mi = 0; mi < 2; ++mi)
        #pragma unroll
        for (int kk = 0; kk < 4; ++kk) {
            long qrow = q0 + wave * 32 + mi * 16 + lrow;
            qf[mi][kk] = *reinterpret_cast<const bfrag8*>(&qb[qrow * rs + kk * 32 + quad * 8]);
        }

    const f32x4 fzero = {0.f, 0.f, 0.f, 0.f};
    f32x4 O[2][8];
    #pragma unroll
    for (int mi = 0; mi < 2; ++mi)
        #pragma unroll
        for (int dt = 0; dt < 8; ++dt) O[mi][dt] = fzero;
    f32x4 mst[2], lst[2];
    #pragma unroll
    for (int mi = 0; mi < 2; ++mi)
        #pragma unroll
        for (int r = 0; r < 4; ++r) { mst[mi][r] = -1e30f; lst[mi][r] = 0.f; }

    const int ntiles = 2 * qt + 2;
    for (int nt = 0; nt < ntiles; ++nt) {
        const int kv0 = nt * 64;
        #pragma unroll
        for (int i = 0; i < 4; ++i) {
            int c = tid + i * 256;
            int row = c >> 4, cc = c & 15;
            u32x4 v = *reinterpret_cast<const u32x4*>(&kb[(long)(kv0 + row) * rs + cc * 8]);
            *reinterpret_cast<u32x4*>(&Ks[row * LDK + cc * 8]) = v;
        }
        #pragma unroll
        for (int i = 0; i < 4; ++i) {
            int c = tid + i * 256;
            int row = c >> 4, cc = c & 15;
            u32x4 v = *reinterpret_cast<const u32x4*>(&vb[(long)(kv0 + row) * rs + cc * 8]);
            const ush* pv = reinterpret_cast<const ush*>(&v);
            #pragma unroll
            for (int j = 0; j < 8; ++j)
                Vt[(cc * 8 + j) * LDV + row] = pv[j];
        }
        __syncthreads();

        f32x4 sv[2][4];
        #pragma unroll
        for (int ni = 0; ni < 4; ++ni) {
            bfrag8 kf[4];
            #pragma unroll
            for (int kk = 0; kk < 4; ++kk)
                kf[kk] = *reinterpret_cast<const bfrag8*>(&Ks[(ni * 16 + lrow) * LDK + kk * 32 + quad * 8]);
            #pragma unroll
            for (int mi = 0; mi < 2; ++mi) {
                f32x4 a = fzero;
                #pragma unroll
                for (int kk = 0; kk < 4; ++kk)
                    a = __builtin_amdgcn_mfma_f32_16x16x32_bf16(qf[mi][kk], kf[kk], a, 0, 0, 0);
                sv[mi][ni] = a;
            }
        }

        #pragma unroll
        for (int mi = 0; mi < 2; ++mi)
            #pragma unroll
            for (int ni = 0; ni < 4; ++ni)
                #pragma unroll
                for (int r = 0; r < 4; ++r) {
                    int q  = q0 + wave * 32 + mi * 16 + quad * 4 + r;
                    int kv = kv0 + ni * 16 + lrow;
                    float x = sv[mi][ni][r] * scale;
                    sv[mi][ni][r] = (kv <= q) ? x : -1e30f;
                }

        #pragma unroll
        for (int mi = 0; mi < 2; ++mi) {
            f32x4 rmax;
            #pragma unroll
            for (int r = 0; r < 4; ++r)
                rmax[r] = fmaxf(fmaxf(sv[mi][0][r], sv[mi][1][r]),
                                fmaxf(sv[mi][2][r], sv[mi][3][r]));
            #pragma unroll
            for (int off = 1; off < 16; off <<= 1)
                #pragma unroll
                for (int r = 0; r < 4; ++r)
                    rmax[r] = fmaxf(rmax[r], __shfl_xor(rmax[r], off, 64));

            f32x4 mnew, alpha;
            #pragma unroll
            for (int r = 0; r < 4; ++r) {
                mnew[r]  = fmaxf(mst[mi][r], rmax[r]);
                alpha[r] = __expf(mst[mi][r] - mnew[r]);
            }
            f32x4 rsum = fzero;
            #pragma unroll
            for (int ni = 0; ni < 4; ++ni)
                #pragma unroll
                for (int r = 0; r < 4; ++r) {
                    float p = __expf(sv[mi][ni][r] - mnew[r]);
                    sv[mi][ni][r] = p;
                    rsum[r] += p;
                }
            #pragma unroll
            for (int off = 1; off < 16; off <<= 1)
                #pragma unroll
                for (int r = 0; r < 4; ++r)
                    rsum[r] += __shfl_xor(rsum[r], off, 64);
            #pragma unroll
            for (int r = 0; r < 4; ++r) {
                lst[mi][r] = lst[mi][r] * alpha[r] + rsum[r];
                mst[mi][r] = mnew[r];
            }
            #pragma unroll
            for (int dt = 0; dt < 8; ++dt)
                #pragma unroll
                for (int r = 0; r < 4; ++r)
                    O[mi][dt][r] *= alpha[r];
            #pragma unroll
            for (int ni = 0; ni < 4; ++ni)
                #pragma unroll
                for (int r = 0; r < 4; ++r)
                    Ps[(wave * 32 + mi * 16 + quad * 4 + r) * LDP + ni * 16 + lrow]
                        = f2bf(sv[mi][ni][r]);
        }

        __syncthreads();

        bfrag8 pf[2][2];
        #pragma unroll
        for (int mi = 0; mi < 2; ++mi)
            #pragma unroll
            for (int nk = 0; nk < 2; ++nk)
                pf[mi][nk] = *reinterpret_cast<const bfrag8*>(
                    &Ps[(wave * 32 + mi * 16 + lrow) * LDP + nk * 32 + quad * 8]);
        #pragma unroll
        for (int dt = 0; dt < 8; ++dt) {
            bfrag8 vf[2];
            #pragma unroll
            for (int nk = 0; nk < 2; ++nk)
                vf[nk] = *reinterpret_cast<const bfrag8*>(
                    &Vt[(dt * 16 + lrow) * LDV + nk * 32 + quad * 8]);
            #pragma unroll
            for (int mi = 0; mi < 2; ++mi)
                #pragma unroll
                for (int nk = 0; nk < 2; ++nk)
                    O[mi][dt] = __builtin_amdgcn_mfma_f32_16x16x32_bf16(pf[mi][nk], vf[nk], O[mi][dt], 0, 0, 0);
        }
        __syncthreads();
    }

    #pragma unroll
    for (int mi = 0; mi < 2; ++mi)
        #pragma unroll
        for (int r = 0; r < 4; ++r) {
            float inv = 1.0f / lst[mi][r];
            long q = q0 + wave * 32 + mi * 16 + quad * 4 + r;
            long base = (long)(b * 2048 + q) * 4096 + h * 128 + lrow;
            #pragma unroll
            for (int dt = 0; dt < 8; ++dt)
                y[base + dt * 16] = f2bf(O[mi][dt][r] * inv);
        }
}

// ---------------------------------------------------------------------------
extern "C" void kernel_launch(void* const* d_in, const int* in_sizes, int n_in,
                              void* d_out, int out_size, void* d_ws, size_t ws_size,
                              hipStream_t stream)
{
    const float* x  = (const float*)d_in[0];   // (2,2048,4096) fp32
    const float* wa = (const float*)d_in[1];   // (4096,12288) fp32
    const float* wp = (const float*)d_in[2];   // (4096,4096) fp32
    const float* fc = (const float*)d_in[3];   // (2048,64) fp32
    const float* fs = (const float*)d_in[4];   // (2048,64) fp32
    float* out = (float*)d_out;                // (2,2048,4096) fp32

    ush* qkv = (ush*)d_ws;                     // 4096 x 12288 bf16 (100.7 MB)
    ush* y   = qkv + (size_t)4096 * 12288;     // 4096 x 4096 bf16  (33.6 MB)

    // 1. qkv = x @ w_atten  (fp32 in, bf16 out)
    gemm_ff_bf<<<dim3(12288 / BN, 4096 / BM), 256, 0, stream>>>(x, wa, qkv, 4096, 12288, 4096);
    // 2. RoPE in-place on q,k
    rope_kernel<<<8388608 / 256, 256, 0, stream>>>(qkv, fc, fs);
    // 3. causal flash attention -> y (bf16)
    attn_kernel<<<dim3(16, 64), 256, 0, stream>>>(qkv, y);
    // 4. out = y @ w_proj  (bf16 x fp32 in, fp32 out)
    gemm_bf_f<<<dim3(4096 / BN, 4096 / BM), 256, 0, stream>>>(y, wp, out, 4096, 4096, 4096);
}